// Round 10
// baseline (211.352 us; speedup 1.0000x reference)
//
#include <hip/hip_runtime.h>

// out[r,f] = bias[f] + sum_{i: rows[i]==r} value[i] * weight[cols[i], f]
// R18 pipeline (3 kernels): k_init -> k_bin_fixed (CH=8192, full-line runs)
// -> k_spmm11 (balanced-range consume: each 16-lane group owns a fixed 1/32
// slice of the row-sorted chunk; seam rows flushed via ds_add_f32).
// History: R9/R11: LDS atomic accumulate -> 1310us dead end (but ds_fadd +
// explicit lgkmcnt drain is correct and fine at LOW volume). R14/R16: any
// LDS growth dropping 4->3 blocks/CU regresses (TLP-bound). R15: cursor
// padding null; bin fixed by CH=8192 (write fragmentation). R17: 8-wide
// batch spilled to scratch under the 64-VGPR cap (WRITE_SIZE 25->47MB),
// 69us. R18: per-row walk had ~33% exec-mask idle (max of 4 Poisson group
// trip counts); balanced ranges equalize trip counts, 4-wide loads kept.
//
// pair pack (u64): val[63:32] | fine[29:20] | lr[19:13] | col[12:0]

#define NBF 1024
#define DMAX 128     // lr 7 bits => d <= 128 (n <= 131072)
#define CH 8192      // binning chunk (8/thread)
#define CC 1536      // consumer sort chunk (3/thread, 4 blocks/CU)
#define SP_T 512
#define CSTR 16      // cursorF stride (ints)

__device__ __forceinline__ void ds_fadd(float* p, float v) {
    unsigned a = (unsigned)(unsigned long long)p;  // LDS byte offset
    asm volatile("ds_add_f32 %0, %1" :: "v"(a), "v"(v) : "memory");
}

__global__ void k_init(int* __restrict__ cursorF, int* __restrict__ ovfCnt, int slots) {
    cursorF[threadIdx.x * CSTR] = threadIdx.x * slots;
    if (threadIdx.x == 0) *ovfCnt = 0;
}

// Single-pass fine bin into fixed-stride bucket slots. Per-chunk LDS hist +
// scan + stage; one global atomicAdd per (block,bin) reserves space; spill
// to ovf on window overflow (statistically never for uniform rows).
__global__ __launch_bounds__(1024) void k_bin_fixed(const int* __restrict__ rows,
        const int* __restrict__ cols, const float* __restrict__ vals, int nnz,
        unsigned M, int S, int d, int slots, int* __restrict__ cursorF,
        unsigned long long* __restrict__ pairs1, int* __restrict__ ovfCnt,
        unsigned long long* __restrict__ ovf) {
    __shared__ unsigned long long stage[CH];       // 64 KB
    __shared__ int histF[NBF], scF[NBF], adjF[NBF];// 12 KB
    __shared__ int wsum[16];
    int t = threadIdx.x, lane = t & 63, wv = t >> 6;
    long long base = (long long)blockIdx.x * CH;
    int count = (int)min((long long)CH, (long long)nnz - base);
    histF[t] = 0;
    __syncthreads();
    int f8[8], rk8[8];
    unsigned long long pk8[8];
#pragma unroll
    for (int k = 0; k < 8; ++k) {
        int i = t + (k << 10);
        f8[k] = -1;
        if (i < count) {
            unsigned r = (unsigned)rows[base + i];
            int c = cols[base + i];
            float vv = vals[base + i];
            int f = (int)(((unsigned long long)r * M) >> S);
            int lr = (int)r - f * d;
            f8[k] = f;
            rk8[k] = atomicAdd(&histF[f], 1);
            pk8[k] = ((unsigned long long)__float_as_uint(vv) << 32) |
                     ((unsigned)f << 20) | ((unsigned)lr << 13) | (unsigned)c;
        }
    }
    __syncthreads();
    int v = histF[t], x = v;
#pragma unroll
    for (int off = 1; off < 64; off <<= 1) {
        int y = __shfl_up(x, off, 64);
        if (lane >= off) x += y;
    }
    if (lane == 63) wsum[wv] = x;
    __syncthreads();
    if (t < 16) {
        int s = wsum[t], xs = s;
#pragma unroll
        for (int off = 1; off < 16; off <<= 1) {
            int y = __shfl_up(xs, off, 16);
            if (t >= off) xs += y;
        }
        wsum[t] = xs - s;
    }
    __syncthreads();
    int incl = x + wsum[wv];
    scF[t] = incl;
    if (v > 0) {
        int g = atomicAdd(&cursorF[t * CSTR], v);
        adjF[t] = g - (incl - v);
    }
    __syncthreads();
#pragma unroll
    for (int k = 0; k < 8; ++k)
        if (f8[k] >= 0) stage[(scF[f8[k]] - histF[f8[k]]) + rk8[k]] = pk8[k];
    __syncthreads();
    for (int i = t; i < count; i += 1024) {
        unsigned long long p = stage[i];
        int f = (int)((p >> 20) & 1023);
        int dest = adjF[f] + i;
        if (dest < (f + 1) * slots) pairs1[dest] = p;
        else ovf[atomicAdd(ovfCnt, 1)] = p;
    }
}

// Consumer: CC=1536, 38.4 KB LDS -> 4 blocks/CU. Sort chunk by local row
// (int LDS atomics + shfl scan, as spmm5). Consume: each 16-lane group owns
// slice [g*Q, (g+1)*Q) of the SORTED stage -> identical trip counts, zero
// divergence waste. Interior rows are group-exclusive (plain RMW); first/
// last row of a slice may be shared -> ds_add_f32 (atomic, fire-forget),
// drained per chunk (seam-row ownership can change next chunk).
__global__ __launch_bounds__(SP_T, 8) void k_spmm11(
        const unsigned long long* __restrict__ pairs, const int* __restrict__ cursorF,
        const int* __restrict__ ovfCnt, const unsigned long long* __restrict__ ovf,
        const float* __restrict__ weight, const float* __restrict__ bias,
        float* __restrict__ out, int d, int n, int slots) {
    __shared__ unsigned long long stage[CC];   // 12 KB
    __shared__ int histR[DMAX], scR[DMAX];     // 1 KB
    extern __shared__ float acc[];             // d*64 floats (25 KB @ d=98)
    int b = blockIdx.x, t = threadIdx.x;
    int row0 = b * d;
    if (row0 >= n) return;
    int nrows = min(d, n - row0);
    long long sbase = (long long)b * slots;
    int cnt = cursorF[b * CSTR] - (int)sbase;
    if (cnt > slots) cnt = slots;
    if (cnt < 0) cnt = 0;

    for (int i = t; i < (nrows << 6); i += SP_T) acc[i] = 0.0f;

    int g = t >> 4, fq = t & 15;
    const float* wbase = weight + (fq << 2);

    for (int cb = 0; cb < cnt; cb += CC) {
        int ccnt = min(CC, cnt - cb);
        if (t < DMAX) histR[t] = 0;
        __syncthreads();
        int lr3[3], rk3[3];
        unsigned long long pk3[3];
#pragma unroll
        for (int k = 0; k < 3; ++k) {
            int i = t + (k << 9);
            lr3[k] = -1;
            if (i < ccnt) {
                unsigned long long p = pairs[sbase + cb + i];
                int lr = (int)((p >> 13) & 127);
                lr3[k] = lr;
                rk3[k] = atomicAdd(&histR[lr], 1);
                pk3[k] = p;
            }
        }
        __syncthreads();
        if (t < DMAX) {
            int v = histR[t], x = v;
            int lane = t & 63;
#pragma unroll
            for (int off = 1; off < 64; off <<= 1) {
                int y = __shfl_up(x, off, 64);
                if (lane >= off) x += y;
            }
            scR[t] = x;
        }
        __syncthreads();
        if (t >= 64 && t < DMAX) scR[t] += scR[63];
        __syncthreads();
#pragma unroll
        for (int k = 0; k < 3; ++k)
            if (lr3[k] >= 0) stage[(scR[lr3[k]] - histR[lr3[k]]) + rk3[k]] = pk3[k];
        __syncthreads();

        // balanced-range consume
        int Q = (ccnt + 31) >> 5;
        int lo = g * Q, hi = min(lo + Q, ccnt);
        if (lo < hi) {
            int firstRow = (int)((stage[lo] >> 13) & 127);
            int lastRow  = (int)((stage[hi - 1] >> 13) & 127);
            int cr = firstRow;
            float4 a = {0.0f, 0.0f, 0.0f, 0.0f};
            int j = lo;
#define STEP(qv, wv4)                                                     \
            {                                                             \
                int lr_ = (int)(((qv) >> 13) & 127);                      \
                if (lr_ != cr) {                                          \
                    float* ap_ = &acc[(cr << 6) + (fq << 2)];             \
                    if (cr == firstRow || cr == lastRow) {                \
                        ds_fadd(ap_ + 0, a.x); ds_fadd(ap_ + 1, a.y);     \
                        ds_fadd(ap_ + 2, a.z); ds_fadd(ap_ + 3, a.w);     \
                    } else {                                              \
                        float4 o_ = *(float4*)ap_;                        \
                        o_.x += a.x; o_.y += a.y; o_.z += a.z; o_.w += a.w; \
                        *(float4*)ap_ = o_;                               \
                    }                                                     \
                    a.x = 0.0f; a.y = 0.0f; a.z = 0.0f; a.w = 0.0f;       \
                    cr = lr_;                                             \
                }                                                         \
                float vv_ = __uint_as_float((unsigned)((qv) >> 32));      \
                a.x = fmaf(vv_, (wv4).x, a.x); a.y = fmaf(vv_, (wv4).y, a.y); \
                a.z = fmaf(vv_, (wv4).z, a.z); a.w = fmaf(vv_, (wv4).w, a.w); \
            }
            for (; j + 4 <= hi; j += 4) {
                unsigned long long q0 = stage[j + 0], q1 = stage[j + 1];
                unsigned long long q2 = stage[j + 2], q3 = stage[j + 3];
                const float4 w0 = *(const float4*)(wbase + ((int)(q0 & 8191) << 6));
                const float4 w1 = *(const float4*)(wbase + ((int)(q1 & 8191) << 6));
                const float4 w2 = *(const float4*)(wbase + ((int)(q2 & 8191) << 6));
                const float4 w3 = *(const float4*)(wbase + ((int)(q3 & 8191) << 6));
                STEP(q0, w0); STEP(q1, w1); STEP(q2, w2); STEP(q3, w3);
            }
            for (; j < hi; ++j) {
                unsigned long long q = stage[j];
                const float4 w = *(const float4*)(wbase + ((int)(q & 8191) << 6));
                STEP(q, w);
            }
#undef STEP
            // final flush (cr row): seam-safe
            {
                float* ap_ = &acc[(cr << 6) + (fq << 2)];
                if (cr == firstRow || cr == lastRow) {
                    ds_fadd(ap_ + 0, a.x); ds_fadd(ap_ + 1, a.y);
                    ds_fadd(ap_ + 2, a.z); ds_fadd(ap_ + 3, a.w);
                } else {
                    float4 o_ = *(float4*)ap_;
                    o_.x += a.x; o_.y += a.y; o_.z += a.z; o_.w += a.w;
                    *(float4*)ap_ = o_;
                }
            }
        }
        // drain OUR inline-asm ds_adds before the chunk barrier: seam-row
        // ownership may change next chunk (plain RMW would race a pending add)
        asm volatile("s_waitcnt lgkmcnt(0)" ::: "memory");
        __builtin_amdgcn_sched_barrier(0);
        __syncthreads();
    }

    // overflow (spilled pairs): statistically empty for uniform rows.
    int oc = *ovfCnt;
    if (oc > 0) {
        for (int i = g; i < oc; i += (SP_T >> 4)) {
            unsigned long long p = ovf[i];
            if ((int)((p >> 20) & 1023) == b) {
                int lr = (int)((p >> 13) & 127);
                int cc = (int)(p & 8191);
                float vv = __uint_as_float((unsigned)(p >> 32));
                const float4 w = *(const float4*)(weight + (cc << 6) + (fq << 2));
                float* ap = &acc[(lr << 6) + (fq << 2)];
                ds_fadd(ap + 0, vv * w.x); ds_fadd(ap + 1, vv * w.y);
                ds_fadd(ap + 2, vv * w.z); ds_fadd(ap + 3, vv * w.w);
            }
        }
        asm volatile("s_waitcnt lgkmcnt(0)" ::: "memory");
        __builtin_amdgcn_sched_barrier(0);
    }
    __syncthreads();

    for (int i = t; i < (nrows << 6); i += SP_T)
        out[((long long)row0 << 6) + i] = acc[i] + bias[i & 63];
}

extern "C" void kernel_launch(void* const* d_in, const int* in_sizes, int n_in,
                              void* d_out, int out_size, void* d_ws, size_t ws_size,
                              hipStream_t stream) {
    const int*   index  = (const int*)d_in[0];
    const float* value  = (const float*)d_in[1];
    const float* weight = (const float*)d_in[3];
    const float* bias   = (const float*)d_in[4];
    float*       out    = (float*)d_out;

    int nnz = in_sizes[0] / 2;
    int n   = out_size / 64;
    const int* rows = index;
    const int* cols = index + nnz;

    int d = (n + NBF - 1) / NBF;  // 98 for n=100000 (<= DMAX)
    unsigned M = 0;
    int S = 0;
    for (S = 20; S <= 40; ++S) {
        unsigned long long m = ((1ull << S) + (unsigned)d - 1) / (unsigned)d;
        unsigned long long e = m * (unsigned long long)d - (1ull << S);
        if (m <= 0xffffffffull && e * (unsigned long long)(n > 0 ? n - 1 : 0) < (1ull << S)) {
            M = (unsigned)m;
            break;
        }
    }

    int nChunks = (nnz + CH - 1) / CH;
    char* ws = (char*)d_ws;
    int* cursorF = (int*)ws;                  // 64 KB (1024 counters, 64B stride)
    int* ovfCnt  = (int*)(ws + (64 << 10));
    unsigned long long* pairsS = (unsigned long long*)(ws + (128 << 10));

    size_t szOvf = (((size_t)nnz * 8) + 255) & ~(size_t)255;
    size_t availS = (ws_size > (128 << 10) + szOvf) ? (ws_size - (128 << 10) - szOvf) : 0;
    long long slotsL = (long long)(availS / ((size_t)NBF * 8));
    int slots = (int)(slotsL > 6144 ? 6144 : slotsL);
    if (slots > 64) slots &= ~63;
    if (slots < 1) slots = 1;
    unsigned long long* ovf = (unsigned long long*)(ws + (128 << 10) + (size_t)slots * NBF * 8);

    k_init<<<1, 1024, 0, stream>>>(cursorF, ovfCnt, slots);
    k_bin_fixed<<<nChunks, 1024, 0, stream>>>(rows, cols, value, nnz, M, S, d, slots,
                                              cursorF, pairsS, ovfCnt, ovf);
    size_t smem = (size_t)d * 64 * sizeof(float);
    k_spmm11<<<NBF, SP_T, smem, stream>>>(pairsS, cursorF, ovfCnt, ovf, weight, bias,
                                          out, d, n, slots);
}

// Round 11
// 174.143 us; speedup vs baseline: 1.2137x; 1.2137x over previous
//
#include <hip/hip_runtime.h>

// out[r,f] = bias[f] + sum_{i: rows[i]==r} value[i] * weight[cols[i], f]
// R19 pipeline (3 kernels): k_init -> k_bin_fixed (CH=8192, full-line runs,
// ~44us, R16/R17-verified) -> k_spmm9 (spmm5-structure consumer, CC=1536,
// whole-row walk, 4-wide batches, 4 blocks/CU, 60-62us, R0/R13/R15-verified).
// First time both verified-best halves run together.
// Consumer-rewrite ledger (all regressed, do not retry):
//   R14 double-buffer rank||consume: 69us (LDS 4->3 blocks/CU, TLP-bound)
//   R16 CC=3072: 69us (same occupancy cliff)
//   R17 8-wide batch: 69us (VGPR spill to scratch, WRITE 25->47MB)
//   R18 balanced-range + per-element flush branch: 96us (branch between
//       every load+FMA kills 4-wide load batching; cross-group divergence)
// Front-end ledger: R9/R11 LDS fp-atomic accumulate 1310us (atomic pipe
// ~3cyc/lane); R15 cursor padding null; CH=4096 32B-run write fragmentation
// fixed by CH=8192 (WRITE 80->50MB, 63->44us).
//
// pair pack (u64): val[63:32] | fine[29:20] | lr[19:13] | col[12:0]

#define NBF 1024
#define DMAX 128     // lr 7 bits => d <= 128 (n <= 131072)
#define CH 8192      // binning chunk (8/thread)
#define CC 1536      // consumer sort chunk (3/thread, 4 blocks/CU)
#define SP_T 512
#define CSTR 16      // cursorF stride (ints)

__device__ __forceinline__ void ds_fadd(float* p, float v) {
    unsigned a = (unsigned)(unsigned long long)p;  // LDS byte offset
    asm volatile("ds_add_f32 %0, %1" :: "v"(a), "v"(v) : "memory");
}

__global__ void k_init(int* __restrict__ cursorF, int* __restrict__ ovfCnt, int slots) {
    cursorF[threadIdx.x * CSTR] = threadIdx.x * slots;
    if (threadIdx.x == 0) *ovfCnt = 0;
}

// Single-pass fine bin into fixed-stride bucket slots. Per-chunk LDS hist +
// scan + stage; one global atomicAdd per (block,bin) reserves space; spill
// to ovf on window overflow (statistically never for uniform rows).
__global__ __launch_bounds__(1024) void k_bin_fixed(const int* __restrict__ rows,
        const int* __restrict__ cols, const float* __restrict__ vals, int nnz,
        unsigned M, int S, int d, int slots, int* __restrict__ cursorF,
        unsigned long long* __restrict__ pairs1, int* __restrict__ ovfCnt,
        unsigned long long* __restrict__ ovf) {
    __shared__ unsigned long long stage[CH];       // 64 KB
    __shared__ int histF[NBF], scF[NBF], adjF[NBF];// 12 KB
    __shared__ int wsum[16];
    int t = threadIdx.x, lane = t & 63, wv = t >> 6;
    long long base = (long long)blockIdx.x * CH;
    int count = (int)min((long long)CH, (long long)nnz - base);
    histF[t] = 0;
    __syncthreads();
    int f8[8], rk8[8];
    unsigned long long pk8[8];
#pragma unroll
    for (int k = 0; k < 8; ++k) {
        int i = t + (k << 10);
        f8[k] = -1;
        if (i < count) {
            unsigned r = (unsigned)rows[base + i];
            int c = cols[base + i];
            float vv = vals[base + i];
            int f = (int)(((unsigned long long)r * M) >> S);
            int lr = (int)r - f * d;
            f8[k] = f;
            rk8[k] = atomicAdd(&histF[f], 1);
            pk8[k] = ((unsigned long long)__float_as_uint(vv) << 32) |
                     ((unsigned)f << 20) | ((unsigned)lr << 13) | (unsigned)c;
        }
    }
    __syncthreads();
    int v = histF[t], x = v;
#pragma unroll
    for (int off = 1; off < 64; off <<= 1) {
        int y = __shfl_up(x, off, 64);
        if (lane >= off) x += y;
    }
    if (lane == 63) wsum[wv] = x;
    __syncthreads();
    if (t < 16) {
        int s = wsum[t], xs = s;
#pragma unroll
        for (int off = 1; off < 16; off <<= 1) {
            int y = __shfl_up(xs, off, 16);
            if (t >= off) xs += y;
        }
        wsum[t] = xs - s;
    }
    __syncthreads();
    int incl = x + wsum[wv];
    scF[t] = incl;
    if (v > 0) {
        int g = atomicAdd(&cursorF[t * CSTR], v);
        adjF[t] = g - (incl - v);
    }
    __syncthreads();
#pragma unroll
    for (int k = 0; k < 8; ++k)
        if (f8[k] >= 0) stage[(scF[f8[k]] - histF[f8[k]]) + rk8[k]] = pk8[k];
    __syncthreads();
    for (int i = t; i < count; i += 1024) {
        unsigned long long p = stage[i];
        int f = (int)((p >> 20) & 1023);
        int dest = adjF[f] + i;
        if (dest < (f + 1) * slots) pairs1[dest] = p;
        else ovf[atomicAdd(ovfCnt, 1)] = p;
    }
}

// Consumer: spmm5 structure on fixed-slot layout (R15 k_spmm9 verbatim).
// CC=1536, 38.4 KB LDS -> 4 blocks/CU. Sort chunk by local row (int LDS
// atomics + shfl scan), then 16-lane groups walk whole rows with 4-wide
// batched weight loads. Overflow tail via ds_add_f32 + explicit lgkmcnt
// drain (R11 lesson: inline-asm DS ops invisible to waitcnt scoreboard).
__global__ __launch_bounds__(SP_T, 8) void k_spmm9(
        const unsigned long long* __restrict__ pairs, const int* __restrict__ cursorF,
        const int* __restrict__ ovfCnt, const unsigned long long* __restrict__ ovf,
        const float* __restrict__ weight, const float* __restrict__ bias,
        float* __restrict__ out, int d, int n, int slots) {
    __shared__ unsigned long long stage[CC];   // 12 KB
    __shared__ int histR[DMAX], scR[DMAX];     // 1 KB
    extern __shared__ float acc[];             // d*64 floats (25 KB @ d=98)
    int b = blockIdx.x, t = threadIdx.x;
    int row0 = b * d;
    if (row0 >= n) return;
    int nrows = min(d, n - row0);
    long long sbase = (long long)b * slots;
    int cnt = cursorF[b * CSTR] - (int)sbase;
    if (cnt > slots) cnt = slots;
    if (cnt < 0) cnt = 0;

    for (int i = t; i < (nrows << 6); i += SP_T) acc[i] = 0.0f;

    int g = t >> 4, fq = t & 15;
    for (int cb = 0; cb < cnt; cb += CC) {
        int ccnt = min(CC, cnt - cb);
        if (t < DMAX) histR[t] = 0;
        __syncthreads();
        int lr3[3], rk3[3];
        unsigned long long pk3[3];
#pragma unroll
        for (int k = 0; k < 3; ++k) {
            int i = t + (k << 9);
            lr3[k] = -1;
            if (i < ccnt) {
                unsigned long long p = pairs[sbase + cb + i];
                int lr = (int)((p >> 13) & 127);
                lr3[k] = lr;
                rk3[k] = atomicAdd(&histR[lr], 1);
                pk3[k] = p;
            }
        }
        __syncthreads();
        if (t < DMAX) {
            int v = histR[t], x = v;
            int lane = t & 63;
#pragma unroll
            for (int off = 1; off < 64; off <<= 1) {
                int y = __shfl_up(x, off, 64);
                if (lane >= off) x += y;
            }
            scR[t] = x;
        }
        __syncthreads();
        if (t >= 64 && t < DMAX) scR[t] += scR[63];
        __syncthreads();
#pragma unroll
        for (int k = 0; k < 3; ++k)
            if (lr3[k] >= 0) stage[(scR[lr3[k]] - histR[lr3[k]]) + rk3[k]] = pk3[k];
        __syncthreads();

        for (int r = g; r < nrows; r += 32) {
            int e = scR[r], s = e - histR[r];
            if (s >= e) continue;
            float4 a = {0.0f, 0.0f, 0.0f, 0.0f};
            int j = s;
            for (; j + 4 <= e; j += 4) {
                unsigned long long p0 = stage[j + 0];
                unsigned long long p1 = stage[j + 1];
                unsigned long long p2 = stage[j + 2];
                unsigned long long p3 = stage[j + 3];
                const float4 w0 = *(const float4*)(weight + (((int)(p0 & 8191)) << 6) + (fq << 2));
                const float4 w1 = *(const float4*)(weight + (((int)(p1 & 8191)) << 6) + (fq << 2));
                const float4 w2 = *(const float4*)(weight + (((int)(p2 & 8191)) << 6) + (fq << 2));
                const float4 w3 = *(const float4*)(weight + (((int)(p3 & 8191)) << 6) + (fq << 2));
                float v0 = __uint_as_float((unsigned)(p0 >> 32));
                float v1 = __uint_as_float((unsigned)(p1 >> 32));
                float v2 = __uint_as_float((unsigned)(p2 >> 32));
                float v3 = __uint_as_float((unsigned)(p3 >> 32));
                a.x = fmaf(v0, w0.x, a.x); a.y = fmaf(v0, w0.y, a.y);
                a.z = fmaf(v0, w0.z, a.z); a.w = fmaf(v0, w0.w, a.w);
                a.x = fmaf(v1, w1.x, a.x); a.y = fmaf(v1, w1.y, a.y);
                a.z = fmaf(v1, w1.z, a.z); a.w = fmaf(v1, w1.w, a.w);
                a.x = fmaf(v2, w2.x, a.x); a.y = fmaf(v2, w2.y, a.y);
                a.z = fmaf(v2, w2.z, a.z); a.w = fmaf(v2, w2.w, a.w);
                a.x = fmaf(v3, w3.x, a.x); a.y = fmaf(v3, w3.y, a.y);
                a.z = fmaf(v3, w3.z, a.z); a.w = fmaf(v3, w3.w, a.w);
            }
            for (; j < e; ++j) {
                unsigned long long p = stage[j];
                float vv = __uint_as_float((unsigned)(p >> 32));
                const float4 w = *(const float4*)(weight + (((int)(p & 8191)) << 6) + (fq << 2));
                a.x = fmaf(vv, w.x, a.x); a.y = fmaf(vv, w.y, a.y);
                a.z = fmaf(vv, w.z, a.z); a.w = fmaf(vv, w.w, a.w);
            }
            float4* ap = (float4*)&acc[(r << 6) + (fq << 2)];
            float4 o = *ap;
            o.x += a.x; o.y += a.y; o.z += a.z; o.w += a.w;
            *ap = o;
        }
        __syncthreads();
    }

    // overflow (spilled pairs): statistically empty for uniform rows.
    int oc = *ovfCnt;
    if (oc > 0) {
        __syncthreads();
        for (int i = g; i < oc; i += (SP_T >> 4)) {
            unsigned long long p = ovf[i];
            if ((int)((p >> 20) & 1023) == b) {
                int lr = (int)((p >> 13) & 127);
                int cc = (int)(p & 8191);
                float vv = __uint_as_float((unsigned)(p >> 32));
                const float4 w = *(const float4*)(weight + (cc << 6) + (fq << 2));
                float* ap = &acc[(lr << 6) + (fq << 2)];
                ds_fadd(ap + 0, vv * w.x); ds_fadd(ap + 1, vv * w.y);
                ds_fadd(ap + 2, vv * w.z); ds_fadd(ap + 3, vv * w.w);
            }
        }
        asm volatile("s_waitcnt lgkmcnt(0)" ::: "memory");
        __builtin_amdgcn_sched_barrier(0);
        __syncthreads();
    }

    for (int i = t; i < (nrows << 6); i += SP_T)
        out[((long long)row0 << 6) + i] = acc[i] + bias[i & 63];
}

extern "C" void kernel_launch(void* const* d_in, const int* in_sizes, int n_in,
                              void* d_out, int out_size, void* d_ws, size_t ws_size,
                              hipStream_t stream) {
    const int*   index  = (const int*)d_in[0];
    const float* value  = (const float*)d_in[1];
    const float* weight = (const float*)d_in[3];
    const float* bias   = (const float*)d_in[4];
    float*       out    = (float*)d_out;

    int nnz = in_sizes[0] / 2;
    int n   = out_size / 64;
    const int* rows = index;
    const int* cols = index + nnz;

    int d = (n + NBF - 1) / NBF;  // 98 for n=100000 (<= DMAX)
    unsigned M = 0;
    int S = 0;
    for (S = 20; S <= 40; ++S) {
        unsigned long long m = ((1ull << S) + (unsigned)d - 1) / (unsigned)d;
        unsigned long long e = m * (unsigned long long)d - (1ull << S);
        if (m <= 0xffffffffull && e * (unsigned long long)(n > 0 ? n - 1 : 0) < (1ull << S)) {
            M = (unsigned)m;
            break;
        }
    }

    int nChunks = (nnz + CH - 1) / CH;
    char* ws = (char*)d_ws;
    int* cursorF = (int*)ws;                  // 64 KB (1024 counters, 64B stride)
    int* ovfCnt  = (int*)(ws + (64 << 10));
    unsigned long long* pairsS = (unsigned long long*)(ws + (128 << 10));

    size_t szOvf = (((size_t)nnz * 8) + 255) & ~(size_t)255;
    size_t availS = (ws_size > (128 << 10) + szOvf) ? (ws_size - (128 << 10) - szOvf) : 0;
    long long slotsL = (long long)(availS / ((size_t)NBF * 8));
    int slots = (int)(slotsL > 6144 ? 6144 : slotsL);
    if (slots > 64) slots &= ~63;
    if (slots < 1) slots = 1;
    unsigned long long* ovf = (unsigned long long*)(ws + (128 << 10) + (size_t)slots * NBF * 8);

    k_init<<<1, 1024, 0, stream>>>(cursorF, ovfCnt, slots);
    k_bin_fixed<<<nChunks, 1024, 0, stream>>>(rows, cols, value, nnz, M, S, d, slots,
                                              cursorF, pairsS, ovfCnt, ovf);
    size_t smem = (size_t)d * 64 * sizeof(float);
    k_spmm9<<<NBF, SP_T, smem, stream>>>(pairsS, cursorF, ovfCnt, ovf, weight, bias,
                                         out, d, n, slots);
}

// Round 12
// 160.622 us; speedup vs baseline: 1.3158x; 1.0842x over previous
//
#include <hip/hip_runtime.h>

// out[r,f] = bias[f] + sum_{i: rows[i]==r} value[i] * weight[cols[i], f]
// R20 pipeline (2 kernels + 1 memset): hipMemsetAsync zeroes per-bucket
// counts -> k_bin_fixed (CH=8192, vectorized int4/float4 loads, fixed-stride
// slots + spill) -> k_spmm9 (R19-verbatim consumer: CC=1536, whole-row walk,
// 4-wide batches, 4 blocks/CU, 60us verified).
// Budget (R19 reconciled): bin ~41-44, spmm ~60, init+gaps+harness ~70.
// Consumer-rewrite ledger (all regressed, do not retry):
//   R14 dbuf rank||consume 69us (4->3 blocks/CU); R16 CC=3072 69us (same);
//   R17 8-wide batch 69us (VGPR spill, WRITE 25->47MB); R18 balanced-range
//   per-element flush branch 96us (kills load batching).
// Front-end ledger: R9/R11 LDS fp-atomic accumulate 1310us; R15 cursor
// padding null (atomics overlap stage phase); CH=4096 32B-run write
// fragmentation fixed by CH=8192 (WRITE 80->50MB).
// R20: counts-not-cursors (memset replaces k_init launch) + bin loads
// int4x2/float4x2 (24 -> 6 load insts; consecutive-8 ownership is fine,
// stage position comes from the rank not the owner).
//
// pair pack (u64): val[63:32] | fine[29:20] | lr[19:13] | col[12:0]

#define NBF 1024
#define DMAX 128     // lr 7 bits => d <= 128 (n <= 131072)
#define CH 8192      // binning chunk (8/thread)
#define CC 1536      // consumer sort chunk (3/thread, 4 blocks/CU)
#define SP_T 512

__device__ __forceinline__ void ds_fadd(float* p, float v) {
    unsigned a = (unsigned)(unsigned long long)p;  // LDS byte offset
    asm volatile("ds_add_f32 %0, %1" :: "v"(a), "v"(v) : "memory");
}

// Single-pass fine bin into fixed-stride bucket slots. Per-chunk LDS hist +
// scan + stage; one global atomicAdd per (block,bin) on a per-bucket COUNT
// (zeroed by memset) reserves space; spill to ovf on window overflow
// (statistically never for uniform rows).
__global__ __launch_bounds__(1024) void k_bin_fixed(const int* __restrict__ rows,
        const int* __restrict__ cols, const float* __restrict__ vals, int nnz,
        unsigned M, int S, int d, int slots, int* __restrict__ cntF,
        unsigned long long* __restrict__ pairs1, int* __restrict__ ovfCnt,
        unsigned long long* __restrict__ ovf) {
    __shared__ unsigned long long stage[CH];       // 64 KB
    __shared__ int histF[NBF], scF[NBF], adjF[NBF];// 12 KB
    __shared__ int wsum[16];
    int t = threadIdx.x, lane = t & 63, wv = t >> 6;
    long long base = (long long)blockIdx.x * CH;
    int count = (int)min((long long)CH, (long long)nnz - base);
    histF[t] = 0;
    __syncthreads();
    int f8[8], rk8[8];
    unsigned long long pk8[8];
    if (count == CH) {
        // vectorized: thread owns 8 consecutive elements
        const int4*   r4 = (const int4*)(rows + base);
        const int4*   c4 = (const int4*)(cols + base);
        const float4* v4 = (const float4*)(vals + base);
        int4 ra = r4[t * 2], rb = r4[t * 2 + 1];
        int4 ca = c4[t * 2], cb = c4[t * 2 + 1];
        float4 va = v4[t * 2], vb = v4[t * 2 + 1];
        int   rr[8] = {ra.x, ra.y, ra.z, ra.w, rb.x, rb.y, rb.z, rb.w};
        int   cc[8] = {ca.x, ca.y, ca.z, ca.w, cb.x, cb.y, cb.z, cb.w};
        float vv[8] = {va.x, va.y, va.z, va.w, vb.x, vb.y, vb.z, vb.w};
#pragma unroll
        for (int k = 0; k < 8; ++k) {
            unsigned r = (unsigned)rr[k];
            int f = (int)(((unsigned long long)r * M) >> S);
            int lr = (int)r - f * d;
            f8[k] = f;
            rk8[k] = atomicAdd(&histF[f], 1);
            pk8[k] = ((unsigned long long)__float_as_uint(vv[k]) << 32) |
                     ((unsigned)f << 20) | ((unsigned)lr << 13) | (unsigned)cc[k];
        }
    } else {
#pragma unroll
        for (int k = 0; k < 8; ++k) {
            int i = t + (k << 10);
            f8[k] = -1;
            if (i < count) {
                unsigned r = (unsigned)rows[base + i];
                int c = cols[base + i];
                float vv = vals[base + i];
                int f = (int)(((unsigned long long)r * M) >> S);
                int lr = (int)r - f * d;
                f8[k] = f;
                rk8[k] = atomicAdd(&histF[f], 1);
                pk8[k] = ((unsigned long long)__float_as_uint(vv) << 32) |
                         ((unsigned)f << 20) | ((unsigned)lr << 13) | (unsigned)c;
            }
        }
    }
    __syncthreads();
    int v = histF[t], x = v;
#pragma unroll
    for (int off = 1; off < 64; off <<= 1) {
        int y = __shfl_up(x, off, 64);
        if (lane >= off) x += y;
    }
    if (lane == 63) wsum[wv] = x;
    __syncthreads();
    if (t < 16) {
        int s = wsum[t], xs = s;
#pragma unroll
        for (int off = 1; off < 16; off <<= 1) {
            int y = __shfl_up(xs, off, 16);
            if (t >= off) xs += y;
        }
        wsum[t] = xs - s;
    }
    __syncthreads();
    int incl = x + wsum[wv];
    scF[t] = incl;
    if (v > 0) {
        int g = atomicAdd(&cntF[t], v);
        adjF[t] = t * slots + g - (incl - v);
    }
    __syncthreads();
#pragma unroll
    for (int k = 0; k < 8; ++k)
        if (f8[k] >= 0) stage[(scF[f8[k]] - histF[f8[k]]) + rk8[k]] = pk8[k];
    __syncthreads();
    for (int i = t; i < count; i += 1024) {
        unsigned long long p = stage[i];
        int f = (int)((p >> 20) & 1023);
        int dest = adjF[f] + i;
        if (dest < (f + 1) * slots) pairs1[dest] = p;
        else ovf[atomicAdd(ovfCnt, 1)] = p;
    }
}

// Consumer: R19 k_spmm9 verbatim (60us verified) except cnt is read as a
// per-bucket count. CC=1536, 38.4 KB LDS -> 4 blocks/CU. Sort chunk by
// local row (int LDS atomics + shfl scan), then 16-lane groups walk whole
// rows with 4-wide batched weight loads. Overflow tail via ds_add_f32 +
// explicit lgkmcnt drain (R11 lesson: inline-asm DS ops invisible to the
// compiler's waitcnt scoreboard).
__global__ __launch_bounds__(SP_T, 8) void k_spmm9(
        const unsigned long long* __restrict__ pairs, const int* __restrict__ cntF,
        const int* __restrict__ ovfCnt, const unsigned long long* __restrict__ ovf,
        const float* __restrict__ weight, const float* __restrict__ bias,
        float* __restrict__ out, int d, int n, int slots) {
    __shared__ unsigned long long stage[CC];   // 12 KB
    __shared__ int histR[DMAX], scR[DMAX];     // 1 KB
    extern __shared__ float acc[];             // d*64 floats (25 KB @ d=98)
    int b = blockIdx.x, t = threadIdx.x;
    int row0 = b * d;
    if (row0 >= n) return;
    int nrows = min(d, n - row0);
    long long sbase = (long long)b * slots;
    int cnt = cntF[b];
    if (cnt > slots) cnt = slots;
    if (cnt < 0) cnt = 0;

    for (int i = t; i < (nrows << 6); i += SP_T) acc[i] = 0.0f;

    int g = t >> 4, fq = t & 15;
    for (int cb = 0; cb < cnt; cb += CC) {
        int ccnt = min(CC, cnt - cb);
        if (t < DMAX) histR[t] = 0;
        __syncthreads();
        int lr3[3], rk3[3];
        unsigned long long pk3[3];
#pragma unroll
        for (int k = 0; k < 3; ++k) {
            int i = t + (k << 9);
            lr3[k] = -1;
            if (i < ccnt) {
                unsigned long long p = pairs[sbase + cb + i];
                int lr = (int)((p >> 13) & 127);
                lr3[k] = lr;
                rk3[k] = atomicAdd(&histR[lr], 1);
                pk3[k] = p;
            }
        }
        __syncthreads();
        if (t < DMAX) {
            int v = histR[t], x = v;
            int lane = t & 63;
#pragma unroll
            for (int off = 1; off < 64; off <<= 1) {
                int y = __shfl_up(x, off, 64);
                if (lane >= off) x += y;
            }
            scR[t] = x;
        }
        __syncthreads();
        if (t >= 64 && t < DMAX) scR[t] += scR[63];
        __syncthreads();
#pragma unroll
        for (int k = 0; k < 3; ++k)
            if (lr3[k] >= 0) stage[(scR[lr3[k]] - histR[lr3[k]]) + rk3[k]] = pk3[k];
        __syncthreads();

        for (int r = g; r < nrows; r += 32) {
            int e = scR[r], s = e - histR[r];
            if (s >= e) continue;
            float4 a = {0.0f, 0.0f, 0.0f, 0.0f};
            int j = s;
            for (; j + 4 <= e; j += 4) {
                unsigned long long p0 = stage[j + 0];
                unsigned long long p1 = stage[j + 1];
                unsigned long long p2 = stage[j + 2];
                unsigned long long p3 = stage[j + 3];
                const float4 w0 = *(const float4*)(weight + (((int)(p0 & 8191)) << 6) + (fq << 2));
                const float4 w1 = *(const float4*)(weight + (((int)(p1 & 8191)) << 6) + (fq << 2));
                const float4 w2 = *(const float4*)(weight + (((int)(p2 & 8191)) << 6) + (fq << 2));
                const float4 w3 = *(const float4*)(weight + (((int)(p3 & 8191)) << 6) + (fq << 2));
                float v0 = __uint_as_float((unsigned)(p0 >> 32));
                float v1 = __uint_as_float((unsigned)(p1 >> 32));
                float v2 = __uint_as_float((unsigned)(p2 >> 32));
                float v3 = __uint_as_float((unsigned)(p3 >> 32));
                a.x = fmaf(v0, w0.x, a.x); a.y = fmaf(v0, w0.y, a.y);
                a.z = fmaf(v0, w0.z, a.z); a.w = fmaf(v0, w0.w, a.w);
                a.x = fmaf(v1, w1.x, a.x); a.y = fmaf(v1, w1.y, a.y);
                a.z = fmaf(v1, w1.z, a.z); a.w = fmaf(v1, w1.w, a.w);
                a.x = fmaf(v2, w2.x, a.x); a.y = fmaf(v2, w2.y, a.y);
                a.z = fmaf(v2, w2.z, a.z); a.w = fmaf(v2, w2.w, a.w);
                a.x = fmaf(v3, w3.x, a.x); a.y = fmaf(v3, w3.y, a.y);
                a.z = fmaf(v3, w3.z, a.z); a.w = fmaf(v3, w3.w, a.w);
            }
            for (; j < e; ++j) {
                unsigned long long p = stage[j];
                float vv = __uint_as_float((unsigned)(p >> 32));
                const float4 w = *(const float4*)(weight + (((int)(p & 8191)) << 6) + (fq << 2));
                a.x = fmaf(vv, w.x, a.x); a.y = fmaf(vv, w.y, a.y);
                a.z = fmaf(vv, w.z, a.z); a.w = fmaf(vv, w.w, a.w);
            }
            float4* ap = (float4*)&acc[(r << 6) + (fq << 2)];
            float4 o = *ap;
            o.x += a.x; o.y += a.y; o.z += a.z; o.w += a.w;
            *ap = o;
        }
        __syncthreads();
    }

    // overflow (spilled pairs): statistically empty for uniform rows.
    int oc = *ovfCnt;
    if (oc > 0) {
        __syncthreads();
        for (int i = g; i < oc; i += (SP_T >> 4)) {
            unsigned long long p = ovf[i];
            if ((int)((p >> 20) & 1023) == b) {
                int lr = (int)((p >> 13) & 127);
                int cc = (int)(p & 8191);
                float vv = __uint_as_float((unsigned)(p >> 32));
                const float4 w = *(const float4*)(weight + (cc << 6) + (fq << 2));
                float* ap = &acc[(lr << 6) + (fq << 2)];
                ds_fadd(ap + 0, vv * w.x); ds_fadd(ap + 1, vv * w.y);
                ds_fadd(ap + 2, vv * w.z); ds_fadd(ap + 3, vv * w.w);
            }
        }
        asm volatile("s_waitcnt lgkmcnt(0)" ::: "memory");
        __builtin_amdgcn_sched_barrier(0);
        __syncthreads();
    }

    for (int i = t; i < (nrows << 6); i += SP_T)
        out[((long long)row0 << 6) + i] = acc[i] + bias[i & 63];
}

extern "C" void kernel_launch(void* const* d_in, const int* in_sizes, int n_in,
                              void* d_out, int out_size, void* d_ws, size_t ws_size,
                              hipStream_t stream) {
    const int*   index  = (const int*)d_in[0];
    const float* value  = (const float*)d_in[1];
    const float* weight = (const float*)d_in[3];
    const float* bias   = (const float*)d_in[4];
    float*       out    = (float*)d_out;

    int nnz = in_sizes[0] / 2;
    int n   = out_size / 64;
    const int* rows = index;
    const int* cols = index + nnz;

    int d = (n + NBF - 1) / NBF;  // 98 for n=100000 (<= DMAX)
    unsigned M = 0;
    int S = 0;
    for (S = 20; S <= 40; ++S) {
        unsigned long long m = ((1ull << S) + (unsigned)d - 1) / (unsigned)d;
        unsigned long long e = m * (unsigned long long)d - (1ull << S);
        if (m <= 0xffffffffull && e * (unsigned long long)(n > 0 ? n - 1 : 0) < (1ull << S)) {
            M = (unsigned)m;
            break;
        }
    }

    int nChunks = (nnz + CH - 1) / CH;
    char* ws = (char*)d_ws;
    int* cntF   = (int*)ws;                   // 4 KB (per-bucket counts)
    int* ovfCnt = (int*)(ws + 4096);
    unsigned long long* pairsS = (unsigned long long*)(ws + (128 << 10));

    size_t szOvf = (((size_t)nnz * 8) + 255) & ~(size_t)255;
    size_t availS = (ws_size > (128 << 10) + szOvf) ? (ws_size - (128 << 10) - szOvf) : 0;
    long long slotsL = (long long)(availS / ((size_t)NBF * 8));
    int slots = (int)(slotsL > 6144 ? 6144 : slotsL);
    if (slots > 64) slots &= ~63;
    if (slots < 1) slots = 1;
    unsigned long long* ovf = (unsigned long long*)(ws + (128 << 10) + (size_t)slots * NBF * 8);

    hipMemsetAsync(ws, 0, 8192, stream);  // cntF (4KB) + ovfCnt
    k_bin_fixed<<<nChunks, 1024, 0, stream>>>(rows, cols, value, nnz, M, S, d, slots,
                                              cntF, pairsS, ovfCnt, ovf);
    size_t smem = (size_t)d * 64 * sizeof(float);
    k_spmm9<<<NBF, SP_T, smem, stream>>>(pairsS, cntF, ovfCnt, ovf, weight, bias,
                                         out, d, n, slots);
}

// Round 13
// 160.254 us; speedup vs baseline: 1.3189x; 1.0023x over previous
//
#include <hip/hip_runtime.h>

// out[r,f] = bias[f] + sum_{i: rows[i]==r} value[i] * weight[cols[i], f]
// R21 pipeline (2 kernels + memset): memset counts -> k_bin_fixed (CH=8192,
// vectorized loads, fixed-stride slots + spill) -> k_spmm12 (register
// accumulator + whole-bucket sort: CC=4608 >= max bucket, one rank/scan/
// scatter phase, full-row segments, epilogue from regs).
// Consumer-rewrite ledger (all regressed, do not retry):
//   R14 dbuf rank||consume 69us (4->3 blocks/CU); R16 CC=3072 69us (same);
//   R17 8-wide batch 69us (VGPR spill, WRITE 25->47MB); R18 balanced-range
//   per-element flush branch 96us (kills load batching).
// Front-end ledger: R9/R11 LDS fp-atomic accumulate 1310us; R15 cursor
// padding null; CH=4096 write fragmentation fixed by CH=8192.
// R21 consumer: group g owns rows r==g (mod 32) -> acc = 4 float4 REGISTERS
// (static unroll, rule #20); freed 25KB LDS buys CC=4608 (mu+11sigma) so the
// whole bucket sorts in ONE phase; rank keeps packed (rk<<7|lr) only and
// scatter re-reads pairs from L2 to stay under 64 VGPR (R17 lesson).
//
// pair pack (u64): val[63:32] | fine[29:20] | lr[19:13] | col[12:0]

#define NBF 1024
#define DMAX 128     // lr 7 bits => d <= 128 (n <= 131072)
#define CH 8192      // binning chunk (8/thread)
#define CC 4608      // consumer sort chunk (9/thread; >= max bucket size)
#define SP_T 512

__global__ __launch_bounds__(1024) void k_bin_fixed(const int* __restrict__ rows,
        const int* __restrict__ cols, const float* __restrict__ vals, int nnz,
        unsigned M, int S, int d, int slots, int* __restrict__ cntF,
        unsigned long long* __restrict__ pairs1, int* __restrict__ ovfCnt,
        unsigned long long* __restrict__ ovf) {
    __shared__ unsigned long long stage[CH];       // 64 KB
    __shared__ int histF[NBF], scF[NBF], adjF[NBF];// 12 KB
    __shared__ int wsum[16];
    int t = threadIdx.x, lane = t & 63, wv = t >> 6;
    long long base = (long long)blockIdx.x * CH;
    int count = (int)min((long long)CH, (long long)nnz - base);
    histF[t] = 0;
    __syncthreads();
    int f8[8], rk8[8];
    unsigned long long pk8[8];
    if (count == CH) {
        const int4*   r4 = (const int4*)(rows + base);
        const int4*   c4 = (const int4*)(cols + base);
        const float4* v4 = (const float4*)(vals + base);
        int4 ra = r4[t * 2], rb = r4[t * 2 + 1];
        int4 ca = c4[t * 2], cb = c4[t * 2 + 1];
        float4 va = v4[t * 2], vb = v4[t * 2 + 1];
        int   rr[8] = {ra.x, ra.y, ra.z, ra.w, rb.x, rb.y, rb.z, rb.w};
        int   cc[8] = {ca.x, ca.y, ca.z, ca.w, cb.x, cb.y, cb.z, cb.w};
        float vv[8] = {va.x, va.y, va.z, va.w, vb.x, vb.y, vb.z, vb.w};
#pragma unroll
        for (int k = 0; k < 8; ++k) {
            unsigned r = (unsigned)rr[k];
            int f = (int)(((unsigned long long)r * M) >> S);
            int lr = (int)r - f * d;
            f8[k] = f;
            rk8[k] = atomicAdd(&histF[f], 1);
            pk8[k] = ((unsigned long long)__float_as_uint(vv[k]) << 32) |
                     ((unsigned)f << 20) | ((unsigned)lr << 13) | (unsigned)cc[k];
        }
    } else {
#pragma unroll
        for (int k = 0; k < 8; ++k) {
            int i = t + (k << 10);
            f8[k] = -1;
            if (i < count) {
                unsigned r = (unsigned)rows[base + i];
                int c = cols[base + i];
                float vv = vals[base + i];
                int f = (int)(((unsigned long long)r * M) >> S);
                int lr = (int)r - f * d;
                f8[k] = f;
                rk8[k] = atomicAdd(&histF[f], 1);
                pk8[k] = ((unsigned long long)__float_as_uint(vv) << 32) |
                         ((unsigned)f << 20) | ((unsigned)lr << 13) | (unsigned)c;
            }
        }
    }
    __syncthreads();
    int v = histF[t], x = v;
#pragma unroll
    for (int off = 1; off < 64; off <<= 1) {
        int y = __shfl_up(x, off, 64);
        if (lane >= off) x += y;
    }
    if (lane == 63) wsum[wv] = x;
    __syncthreads();
    if (t < 16) {
        int s = wsum[t], xs = s;
#pragma unroll
        for (int off = 1; off < 16; off <<= 1) {
            int y = __shfl_up(xs, off, 16);
            if (t >= off) xs += y;
        }
        wsum[t] = xs - s;
    }
    __syncthreads();
    int incl = x + wsum[wv];
    scF[t] = incl;
    if (v > 0) {
        int g = atomicAdd(&cntF[t], v);
        adjF[t] = t * slots + g - (incl - v);
    }
    __syncthreads();
#pragma unroll
    for (int k = 0; k < 8; ++k)
        if (f8[k] >= 0) stage[(scF[f8[k]] - histF[f8[k]]) + rk8[k]] = pk8[k];
    __syncthreads();
    for (int i = t; i < count; i += 1024) {
        unsigned long long p = stage[i];
        int f = (int)((p >> 20) & 1023);
        int dest = adjF[f] + i;
        if (dest < (f + 1) * slots) pairs1[dest] = p;
        else ovf[atomicAdd(ovfCnt, 1)] = p;
    }
}

// Consumer v5: register accumulator + whole-bucket sort.
// LDS: stage 36.9KB + histR/scR 1KB = 37.9KB -> 4 blocks/CU.
// Rank: 9/thread, keep packed (rk<<7)|lr only; scatter re-reads pairs (L2).
// Consume: group g walks rows g, g+32, g+64, g+96 (static unroll k=0..3),
// 4-wide batched weight loads, accumulate into areg[k] (float4 registers).
// Epilogue: each group writes its rows from regs (+bias); covers empty rows.
__global__ __launch_bounds__(SP_T, 8) void k_spmm12(
        const unsigned long long* __restrict__ pairs, const int* __restrict__ cntF,
        const int* __restrict__ ovfCnt, const unsigned long long* __restrict__ ovf,
        const float* __restrict__ weight, const float* __restrict__ bias,
        float* __restrict__ out, int d, int n, int slots) {
    __shared__ unsigned long long stage[CC];   // 36.9 KB
    __shared__ int histR[DMAX], scR[DMAX];     // 1 KB
    int b = blockIdx.x, t = threadIdx.x;
    int row0 = b * d;
    if (row0 >= n) return;
    int nrows = min(d, n - row0);
    long long sbase = (long long)b * slots;
    int cnt = cntF[b];
    if (cnt > slots) cnt = slots;
    if (cnt < 0) cnt = 0;

    int g = t >> 4, fq = t & 15;
    const float* wbase = weight + (fq << 2);
    float4 a0 = {0,0,0,0}, a1 = {0,0,0,0}, a2 = {0,0,0,0}, a3 = {0,0,0,0};

    for (int cb = 0; cb < cnt; cb += CC) {
        int ccnt = min(CC, cnt - cb);
        if (t < DMAX) histR[t] = 0;
        __syncthreads();
        int pr9[9];  // (rk<<7)|lr, or -1
#pragma unroll
        for (int k = 0; k < 9; ++k) {
            int i = t + (k << 9);
            pr9[k] = -1;
            if (i < ccnt) {
                unsigned long long p = pairs[sbase + cb + i];
                int lr = (int)((p >> 13) & 127);
                int rk = atomicAdd(&histR[lr], 1);
                pr9[k] = (rk << 7) | lr;
            }
        }
        __syncthreads();
        if (t < DMAX) {
            int v = histR[t], x = v;
            int lane = t & 63;
#pragma unroll
            for (int off = 1; off < 64; off <<= 1) {
                int y = __shfl_up(x, off, 64);
                if (lane >= off) x += y;
            }
            scR[t] = x;
        }
        __syncthreads();
        if (t >= 64 && t < DMAX) scR[t] += scR[63];
        __syncthreads();
#pragma unroll
        for (int k = 0; k < 9; ++k) {
            if (pr9[k] >= 0) {
                int i = t + (k << 9);
                int lr = pr9[k] & 127, rk = pr9[k] >> 7;
                stage[(scR[lr] - histR[lr]) + rk] = pairs[sbase + cb + i];
            }
        }
        __syncthreads();

#define CONSUME_ROW(K)                                                        \
        {                                                                     \
            int r = g + (K << 5);                                             \
            if (r < nrows) {                                                  \
                int e = scR[r], s = e - histR[r];                             \
                float4 a = {0,0,0,0};                                         \
                int j = s;                                                    \
                for (; j + 4 <= e; j += 4) {                                  \
                    unsigned long long p0 = stage[j + 0];                     \
                    unsigned long long p1 = stage[j + 1];                     \
                    unsigned long long p2 = stage[j + 2];                     \
                    unsigned long long p3 = stage[j + 3];                     \
                    const float4 w0 = *(const float4*)(wbase + ((int)(p0 & 8191) << 6)); \
                    const float4 w1 = *(const float4*)(wbase + ((int)(p1 & 8191) << 6)); \
                    const float4 w2 = *(const float4*)(wbase + ((int)(p2 & 8191) << 6)); \
                    const float4 w3 = *(const float4*)(wbase + ((int)(p3 & 8191) << 6)); \
                    float v0 = __uint_as_float((unsigned)(p0 >> 32));         \
                    float v1 = __uint_as_float((unsigned)(p1 >> 32));         \
                    float v2 = __uint_as_float((unsigned)(p2 >> 32));         \
                    float v3 = __uint_as_float((unsigned)(p3 >> 32));         \
                    a.x = fmaf(v0, w0.x, a.x); a.y = fmaf(v0, w0.y, a.y);     \
                    a.z = fmaf(v0, w0.z, a.z); a.w = fmaf(v0, w0.w, a.w);     \
                    a.x = fmaf(v1, w1.x, a.x); a.y = fmaf(v1, w1.y, a.y);     \
                    a.z = fmaf(v1, w1.z, a.z); a.w = fmaf(v1, w1.w, a.w);     \
                    a.x = fmaf(v2, w2.x, a.x); a.y = fmaf(v2, w2.y, a.y);     \
                    a.z = fmaf(v2, w2.z, a.z); a.w = fmaf(v2, w2.w, a.w);     \
                    a.x = fmaf(v3, w3.x, a.x); a.y = fmaf(v3, w3.y, a.y);     \
                    a.z = fmaf(v3, w3.z, a.z); a.w = fmaf(v3, w3.w, a.w);     \
                }                                                             \
                for (; j < e; ++j) {                                          \
                    unsigned long long p = stage[j];                          \
                    float vv = __uint_as_float((unsigned)(p >> 32));          \
                    const float4 w = *(const float4*)(wbase + ((int)(p & 8191) << 6)); \
                    a.x = fmaf(vv, w.x, a.x); a.y = fmaf(vv, w.y, a.y);       \
                    a.z = fmaf(vv, w.z, a.z); a.w = fmaf(vv, w.w, a.w);       \
                }                                                             \
                a##K.x += a.x; a##K.y += a.y; a##K.z += a.z; a##K.w += a.w;   \
            }                                                                 \
        }
        CONSUME_ROW(0) CONSUME_ROW(1) CONSUME_ROW(2) CONSUME_ROW(3)
#undef CONSUME_ROW
        __syncthreads();
    }

    // overflow (spilled pairs): statistically empty for uniform rows.
    int oc = *ovfCnt;
    if (oc > 0) {
        for (int i = 0; i < oc; ++i) {
            unsigned long long p = ovf[i];
            if ((int)((p >> 20) & 1023) == b) {
                int lr = (int)((p >> 13) & 127);
                if ((lr & 31) == g) {
                    int cc = (int)(p & 8191);
                    float vv = __uint_as_float((unsigned)(p >> 32));
                    const float4 w = *(const float4*)(wbase + (cc << 6));
                    int k = lr >> 5;
                    if (k == 0) { a0.x = fmaf(vv, w.x, a0.x); a0.y = fmaf(vv, w.y, a0.y);
                                  a0.z = fmaf(vv, w.z, a0.z); a0.w = fmaf(vv, w.w, a0.w); }
                    else if (k == 1) { a1.x = fmaf(vv, w.x, a1.x); a1.y = fmaf(vv, w.y, a1.y);
                                  a1.z = fmaf(vv, w.z, a1.z); a1.w = fmaf(vv, w.w, a1.w); }
                    else if (k == 2) { a2.x = fmaf(vv, w.x, a2.x); a2.y = fmaf(vv, w.y, a2.y);
                                  a2.z = fmaf(vv, w.z, a2.z); a2.w = fmaf(vv, w.w, a2.w); }
                    else { a3.x = fmaf(vv, w.x, a3.x); a3.y = fmaf(vv, w.y, a3.y);
                                  a3.z = fmaf(vv, w.z, a3.z); a3.w = fmaf(vv, w.w, a3.w); }
                }
            }
        }
    }

    // epilogue: each group writes its owned rows from registers (+bias).
    float4 b4 = *(const float4*)(bias + (fq << 2));
#define WRITE_ROW(K)                                                          \
    {                                                                         \
        int r = g + (K << 5);                                                 \
        if (r < nrows) {                                                      \
            float4 o;                                                         \
            o.x = a##K.x + b4.x; o.y = a##K.y + b4.y;                         \
            o.z = a##K.z + b4.z; o.w = a##K.w + b4.w;                         \
            *(float4*)(out + (((long long)(row0 + r)) << 6) + (fq << 2)) = o; \
        }                                                                     \
    }
    WRITE_ROW(0) WRITE_ROW(1) WRITE_ROW(2) WRITE_ROW(3)
#undef WRITE_ROW
}

extern "C" void kernel_launch(void* const* d_in, const int* in_sizes, int n_in,
                              void* d_out, int out_size, void* d_ws, size_t ws_size,
                              hipStream_t stream) {
    const int*   index  = (const int*)d_in[0];
    const float* value  = (const float*)d_in[1];
    const float* weight = (const float*)d_in[3];
    const float* bias   = (const float*)d_in[4];
    float*       out    = (float*)d_out;

    int nnz = in_sizes[0] / 2;
    int n   = out_size / 64;
    const int* rows = index;
    const int* cols = index + nnz;

    int d = (n + NBF - 1) / NBF;  // 98 for n=100000 (<= DMAX)
    unsigned M = 0;
    int S = 0;
    for (S = 20; S <= 40; ++S) {
        unsigned long long m = ((1ull << S) + (unsigned)d - 1) / (unsigned)d;
        unsigned long long e = m * (unsigned long long)d - (1ull << S);
        if (m <= 0xffffffffull && e * (unsigned long long)(n > 0 ? n - 1 : 0) < (1ull << S)) {
            M = (unsigned)m;
            break;
        }
    }

    int nChunks = (nnz + CH - 1) / CH;
    char* ws = (char*)d_ws;
    int* cntF   = (int*)ws;                   // 4 KB (per-bucket counts)
    int* ovfCnt = (int*)(ws + 4096);
    unsigned long long* pairsS = (unsigned long long*)(ws + (128 << 10));

    size_t szOvf = (((size_t)nnz * 8) + 255) & ~(size_t)255;
    size_t availS = (ws_size > (128 << 10) + szOvf) ? (ws_size - (128 << 10) - szOvf) : 0;
    long long slotsL = (long long)(availS / ((size_t)NBF * 8));
    int slots = (int)(slotsL > 6144 ? 6144 : slotsL);
    if (slots > 64) slots &= ~63;
    if (slots < 1) slots = 1;
    unsigned long long* ovf = (unsigned long long*)(ws + (128 << 10) + (size_t)slots * NBF * 8);

    hipMemsetAsync(ws, 0, 8192, stream);  // cntF (4KB) + ovfCnt
    k_bin_fixed<<<nChunks, 1024, 0, stream>>>(rows, cols, value, nnz, M, S, d, slots,
                                              cntF, pairsS, ovfCnt, ovf);
    k_spmm12<<<NBF, SP_T, 0, stream>>>(pairsS, cntF, ovfCnt, ovf, weight, bias,
                                       out, d, n, slots);
}